// Round 8
// baseline (192.334 us; speedup 1.0000x reference)
//
#include <hip/hip_runtime.h>

typedef __attribute__((ext_vector_type(8))) short bf16x8;
typedef __attribute__((ext_vector_type(4))) float f32x4;
typedef unsigned short u16;

#define NTOK 2048
#define DDIM 1024
#define HDIM 4096
#define KEXP 8

#define BM 320   // covers any realistic expert count in ONE tile (counts ~256±15)
#define BK 64
#define LDSS 72  // LDS row stride in bf16 elems (144B)
#define NDESC 16

__device__ __forceinline__ u16 f2bf(float f) {
  union { float f; unsigned int u; } c; c.f = f;
  unsigned int u = c.u;
  return (u16)((u + 0x7FFFu + ((u >> 16) & 1u)) >> 16);  // RNE
}
__device__ __forceinline__ unsigned pk2(float a, float b) {
  return (unsigned)f2bf(a) | ((unsigned)f2bf(b) << 16);
}

// fenced raw barrier: own DS ops drained, no vmcnt drain, no code motion across
#define BAR() do { \
  asm volatile("s_waitcnt lgkmcnt(0)" ::: "memory"); \
  __builtin_amdgcn_sched_barrier(0); \
  __builtin_amdgcn_s_barrier(); \
  __builtin_amdgcn_sched_barrier(0); \
} while (0)

// ---------------- routing: counting sort + tile worklist ----------------
__global__ void route_kernel(const float* __restrict__ cw, int* __restrict__ offs,
                             int* __restrict__ perm, float* __restrict__ wsel,
                             int* __restrict__ desc) {
  __shared__ int cnt[KEXP];
  __shared__ int base[KEXP];
  const int t = threadIdx.x;  // 256 threads, 8 tokens each
  if (t < KEXP) cnt[t] = 0;
  __syncthreads();
  int eid[8]; float wv[8];
  #pragma unroll
  for (int i = 0; i < 8; i++) {
    const int tok = t * 8 + i;
    const float* p = cw + tok * KEXP;
    int best = 0; float bw = p[0];
    #pragma unroll
    for (int k = 1; k < KEXP; k++) { float v = p[k]; if (v > bw) { bw = v; best = k; } }
    eid[i] = best; wv[i] = bw;
    atomicAdd(&cnt[best], 1);
  }
  __syncthreads();
  if (t == 0) {
    int s = 0, nd = 0;
    for (int k = 0; k < KEXP; k++) {
      const int ck = cnt[k];
      base[k] = s; offs[k] = s;
      for (int m0 = 0; m0 < ck && nd < NDESC; m0 += BM)
        desc[nd++] = (k << 12) | (s + m0);   // pack expert(3b) | slot0(12b)
      s += ck;
    }
    offs[KEXP] = s;
    for (; nd < NDESC; nd++) desc[nd] = -1;
  }
  __syncthreads();
  #pragma unroll
  for (int i = 0; i < 8; i++) {
    const int tok = t * 8 + i;
    const int pos = atomicAdd(&base[eid[i]], 1);
    perm[pos] = tok;
    wsel[pos] = wv[i];
  }
}

// ---------------- gather x rows into expert-sorted bf16 ----------------
__global__ void gather_x(const float* __restrict__ x, const int* __restrict__ perm,
                         u16* __restrict__ Xb) {
  const int slot = blockIdx.x;
  const int tok = perm[slot];
  const int t = threadIdx.x;  // 256
  float4 v = ((const float4*)(x + (size_t)tok * DDIM))[t];
  ushort4 o; o.x = f2bf(v.x); o.y = f2bf(v.y); o.z = f2bf(v.z); o.w = f2bf(v.w);
  ((ushort4*)(Xb + (size_t)slot * DDIM))[t] = o;
}

// ---------------- pass 1: H = silu(X@wg) * (X@wu) ----------------
// 1024 thr = 16 waves (4m x 4n), BM=320, BN=64, BK=64, wave tile 80x16 per matrix.
// Depth-2 pipeline: two B reg sets; tile t+2 issued while tile t computes;
// raw barriers only (no vmcnt(0) drain) -> HBM queue never empties.
__global__ __launch_bounds__(1024, 4) void gemm_swiglu(
    const u16* __restrict__ Xb,
    const float* __restrict__ wg, const float* __restrict__ wu,
    const int* __restrict__ offs, const int* __restrict__ desc,
    u16* __restrict__ Hb) {
  __shared__ u16 As[BM * LDSS];
  __shared__ u16 Bg[64 * LDSS];
  __shared__ u16 Bu[64 * LDSS];

  const int d = desc[blockIdx.y];
  if (d < 0) return;
  const int e = d >> 12;
  const int slot0 = d & 0xFFF;
  const int Msub = offs[e + 1] - slot0;
  const int n0 = blockIdx.x * 64;

  const int t = threadIdx.x;
  const int lane = t & 63;
  const int W = t >> 6;
  const int wm = W >> 2;     // 4 m-strips of 80 rows
  const int wn = W & 3;      // 4 n-strips of 16 cols
  const int l15 = lane & 15;
  const int lhi = lane >> 4;

  // A staging: threads 0..639 -> row t>>1, 32 elems (4x uint4) at (t&1)*32
  const bool do_a = t < 640;
  const int a_row = t >> 1;
  const int a_ck = (t & 1) * 32;
  const u16* a_src = Xb + (size_t)min(slot0 + a_row, NTOK - 1) * DDIM + a_ck;
  u16* a_dst = As + a_row * LDSS + a_ck;

  // B staging: t<512 -> Bg (wg), t>=512 -> Bu (wu). Per thread: 2 cols x 4 k.
  const int tb = t & 511;
  const float* b_base = ((t < 512) ? wg : wu) + (size_t)e * DDIM * HDIM;
  const int b_n2 = (tb & 31) * 2;
  const int b_kk = (tb >> 5) * 4;
  const float* b_src = b_base + (size_t)b_kk * HDIM + n0 + b_n2;
  u16* b_dst = ((t < 512) ? Bg : Bu) + b_n2 * LDSS + b_kk;

  float2 brA[4], brB[4];
  uint4 ar0, ar1, ar2, ar3;
  f32x4 accg[5] = {};
  f32x4 accu[5] = {};

  #define LOADB1(dst, tile) { const float* p_ = b_src + (size_t)(tile) * BK * HDIM; \
    dst[0] = *(const float2*)p_;            dst[1] = *(const float2*)(p_ + HDIM); \
    dst[2] = *(const float2*)(p_ + 2*HDIM); dst[3] = *(const float2*)(p_ + 3*HDIM); }
  #define LOADA1(tile) if (do_a) { const uint4* p_ = (const uint4*)(a_src + (tile) * BK); \
    ar0 = p_[0]; ar1 = p_[1]; ar2 = p_[2]; ar3 = p_[3]; }
  #define WRITEA1() if (do_a) { uint4* d_ = (uint4*)a_dst; \
    d_[0] = ar0; d_[1] = ar1; d_[2] = ar2; d_[3] = ar3; }
  #define WRITEB1(src) { \
    *(uint2*)b_dst = make_uint2(pk2(src[0].x, src[1].x), pk2(src[2].x, src[3].x)); \
    *(uint2*)(b_dst + LDSS) = make_uint2(pk2(src[0].y, src[1].y), pk2(src[2].y, src[3].y)); }
  #define COMPUTE1() { _Pragma("unroll") for (int ks = 0; ks < 2; ks++) { \
      const int kof = ks * 32 + lhi * 8; \
      bf16x8 bg_ = *(const bf16x8*)(Bg + (wn * 16 + l15) * LDSS + kof); \
      bf16x8 bu_ = *(const bf16x8*)(Bu + (wn * 16 + l15) * LDSS + kof); \
      _Pragma("unroll") for (int fm = 0; fm < 5; fm++) { \
        bf16x8 af_ = *(const bf16x8*)(As + (wm * 80 + fm * 16 + l15) * LDSS + kof); \
        accg[fm] = __builtin_amdgcn_mfma_f32_16x16x32_bf16(af_, bg_, accg[fm], 0, 0, 0); \
        accu[fm] = __builtin_amdgcn_mfma_f32_16x16x32_bf16(af_, bu_, accu[fm], 0, 0, 0); } } }

  // prologue: tile0 load+write; tile1 issue
  LOADB1(brA, 0); LOADA1(0);
  WRITEA1(); WRITEB1(brA);
  LOADB1(brB, 1);
  BAR();

  #pragma unroll 1
  for (int it = 0; it < 16; it += 2) {
    // even: issue A(it+1), B(it+2)->brA; compute(it); stage tile it+1 (brB)
    LOADA1(it + 1);
    if (it + 2 < 16) LOADB1(brA, it + 2);
    COMPUTE1();
    BAR();
    WRITEA1(); WRITEB1(brB);
    BAR();
    // odd: issue A(it+2), B(it+3)->brB; compute(it+1); stage tile it+2 (brA)
    if (it + 2 < 16) LOADA1(it + 2);
    if (it + 3 < 16) LOADB1(brB, it + 3);
    COMPUTE1();
    BAR();
    if (it + 2 < 16) {
      WRITEA1(); WRITEB1(brA);
      BAR();
    }
  }
  #undef LOADB1
  #undef LOADA1
  #undef WRITEA1
  #undef WRITEB1
  #undef COMPUTE1

  // epilogue: silu(g)*u -> bf16 Hb  (C/D map: col=lane&15, row=(lane>>4)*4+i)
  #pragma unroll
  for (int fm = 0; fm < 5; fm++) {
    #pragma unroll
    for (int i = 0; i < 4; i++) {
      const int row = wm * 80 + fm * 16 + lhi * 4 + i;
      if (row < Msub) {
        const float g = accg[fm][i];
        const float u = accu[fm][i];
        const float h = (g / (1.0f + __expf(-g))) * u;
        Hb[(size_t)(slot0 + row) * HDIM + n0 + wn * 16 + l15] = f2bf(h);
      }
    }
  }
}

// ---------------- pass 2: Y = (H @ wd) * wsel, split-K=4, scatter-add ----------------
// Same depth-2 pipeline. 1024 thr, 16 waves (4m x 4n), BM=320, BN=64.
__global__ __launch_bounds__(1024, 4) void gemm_down(
    const u16* __restrict__ Hb, const float* __restrict__ wd,
    const int* __restrict__ offs, const int* __restrict__ desc,
    const int* __restrict__ perm, const float* __restrict__ wsel,
    float* __restrict__ y) {
  __shared__ u16 As[BM * LDSS];
  __shared__ u16 Bs[64 * LDSS];

  const int d = desc[blockIdx.y];
  if (d < 0) return;
  const int e = d >> 12;
  const int slot0 = d & 0xFFF;
  const int Msub = offs[e + 1] - slot0;
  const int n0 = blockIdx.x * 64;
  const int kbase = blockIdx.z * (HDIM / 4);

  const float* Wd = wd + (size_t)e * HDIM * DDIM;

  const int t = threadIdx.x;
  const int lane = t & 63;
  const int W = t >> 6;
  const int wm = W >> 2;
  const int wn = W & 3;
  const int l15 = lane & 15;
  const int lhi = lane >> 4;

  const bool do_a = t < 640;
  const int a_row = t >> 1;
  const int a_ck = (t & 1) * 32;
  const u16* a_src = Hb + (size_t)min(slot0 + a_row, NTOK - 1) * HDIM + kbase + a_ck;
  u16* a_dst = As + a_row * LDSS + a_ck;

  // B staging: all 1024 threads: 2 cols x 2 k per thread
  const int b_n2 = (t & 31) * 2;
  const int b_kk = (t >> 5) * 2;
  const float* b_src = Wd + (size_t)(kbase + b_kk) * DDIM + n0 + b_n2;
  u16* b_dst = Bs + b_n2 * LDSS + b_kk;

  float2 brA[2], brB[2];
  uint4 ar0, ar1, ar2, ar3;
  f32x4 acc[5] = {};

  #define LOADB2(dst, tile) { const float* p_ = b_src + (size_t)(tile) * BK * DDIM; \
    dst[0] = *(const float2*)p_; dst[1] = *(const float2*)(p_ + DDIM); }
  #define LOADA2(tile) if (do_a) { const uint4* p_ = (const uint4*)(a_src + (tile) * BK); \
    ar0 = p_[0]; ar1 = p_[1]; ar2 = p_[2]; ar3 = p_[3]; }
  #define WRITEA2() if (do_a) { uint4* d_ = (uint4*)a_dst; \
    d_[0] = ar0; d_[1] = ar1; d_[2] = ar2; d_[3] = ar3; }
  #define WRITEB2(src) { \
    *(unsigned*)b_dst = pk2(src[0].x, src[1].x); \
    *(unsigned*)(b_dst + LDSS) = pk2(src[0].y, src[1].y); }
  #define COMPUTE2() { _Pragma("unroll") for (int ks = 0; ks < 2; ks++) { \
      const int kof = ks * 32 + lhi * 8; \
      bf16x8 bf_ = *(const bf16x8*)(Bs + (wn * 16 + l15) * LDSS + kof); \
      _Pragma("unroll") for (int fm = 0; fm < 5; fm++) { \
        bf16x8 af_ = *(const bf16x8*)(As + (wm * 80 + fm * 16 + l15) * LDSS + kof); \
        acc[fm] = __builtin_amdgcn_mfma_f32_16x16x32_bf16(af_, bf_, acc[fm], 0, 0, 0); } } }

  LOADB2(brA, 0); LOADA2(0);
  WRITEA2(); WRITEB2(brA);
  LOADB2(brB, 1);
  BAR();

  #pragma unroll 1
  for (int it = 0; it < 16; it += 2) {
    LOADA2(it + 1);
    if (it + 2 < 16) LOADB2(brA, it + 2);
    COMPUTE2();
    BAR();
    WRITEA2(); WRITEB2(brB);
    BAR();
    if (it + 2 < 16) LOADA2(it + 2);
    if (it + 3 < 16) LOADB2(brB, it + 3);
    COMPUTE2();
    BAR();
    if (it + 2 < 16) {
      WRITEA2(); WRITEB2(brA);
      BAR();
    }
  }
  #undef LOADB2
  #undef LOADA2
  #undef WRITEA2
  #undef WRITEB2
  #undef COMPUTE2

  // epilogue: scale by routing weight, scatter-add (4 K-quarters, commutative)
  #pragma unroll
  for (int fm = 0; fm < 5; fm++) {
    #pragma unroll
    for (int i = 0; i < 4; i++) {
      const int row = wm * 80 + fm * 16 + lhi * 4 + i;
      if (row < Msub) {
        const int slot = slot0 + row;
        const int tok = perm[slot];
        const float w = wsel[slot];
        atomicAdd(y + (size_t)tok * DDIM + n0 + wn * 16 + l15, acc[fm][i] * w);
      }
    }
  }
}

extern "C" void kernel_launch(void* const* d_in, const int* in_sizes, int n_in,
                              void* d_out, int out_size, void* d_ws, size_t ws_size,
                              hipStream_t stream) {
  const float* x  = (const float*)d_in[0];
  const float* cw = (const float*)d_in[1];
  const float* wg = (const float*)d_in[2];
  const float* wu = (const float*)d_in[3];
  const float* wd = (const float*)d_in[4];
  float* y = (float*)d_out;

  char* ws = (char*)d_ws;
  int* offs   = (int*)ws;                          // 16 ints
  int* desc   = (int*)(ws + 64);                   // 16 ints
  int* perm   = (int*)(ws + 128);                  // 2048 ints
  float* wsel = (float*)(ws + 128 + NTOK * 4);     // 2048 floats
  u16* Xb = (u16*)(ws + 32768);                                    // 4 MB
  u16* Hb = (u16*)(ws + 32768 + (size_t)NTOK * DDIM * 2);          // 16 MB

  hipMemsetAsync(d_out, 0, (size_t)NTOK * DDIM * sizeof(float), stream);
  route_kernel<<<1, 256, 0, stream>>>(cw, offs, perm, wsel, desc);
  gather_x<<<NTOK, 256, 0, stream>>>(x, perm, Xb);
  gemm_swiglu<<<dim3(HDIM / 64, NDESC), 1024, 0, stream>>>(Xb, wg, wu, offs, desc, Hb);
  gemm_down<<<dim3(DDIM / 64, NDESC, 4), 1024, 0, stream>>>(Hb, wd, offs, desc, perm, wsel, y);
}